// Round 9
// baseline (150.557 us; speedup 1.0000x reference)
//
#include <hip/hip_runtime.h>
#include <hip/hip_bf16.h>

#define IN_F   4096
#define OUT_F  4096
#define QBLK   8
#define NBLKS  512
#define NTOK   1024
#define NCENT  2048

#define SPLITK 4
#define KCHUNK (IN_F / SPLITK)   // 1024
#define KITERS (KCHUNK / 32)     // 32

typedef unsigned int u32;
typedef unsigned short u16;
typedef __attribute__((ext_vector_type(8))) short short8;   // 8 bf16 (MFMA A/B frag)
typedef __attribute__((ext_vector_type(4))) float floatx4;  // MFMA C/D frag

// round-to-nearest-even fp32 -> bf16
__device__ __forceinline__ u16 f2bf(float f) {
  union { float f; u32 u; } v; v.f = f;
  u32 u = v.u;
  return (u16)((u + 0x7fffu + ((u >> 16) & 1u)) >> 16);
}

// ---------------------------------------------------------------------------
// cast x fp32 -> bf16 in MFMA-fragment-ordered layout:
//   elem (m,k) -> [(m>>4)*512 + (k>>3)]*128 + (m&15)*8 + (k&7)
// A wave's A-fragment load becomes ONE contiguous 1 KB global_load_dwordx4.
// ---------------------------------------------------------------------------
__global__ __launch_bounds__(256) void cast_swz_kernel(
    const float* __restrict__ src, u16* __restrict__ dst) {
  __shared__ __align__(16) u16 ls[256 * 8];      // 256 chunks of 16 B = 4 KB
  const int b = blockIdx.x;
  const int mg = b >> 5;          // m-group 0..63
  const int kq = b & 31;          // k-chunk of 128 elems, 0..31
  const int t = threadIdx.x;
  const int ml = t >> 4;          // m within group 0..15
  const int kbl = t & 15;         // quant block within chunk 0..15

  const float* p = src + (size_t)(mg * 16 + ml) * IN_F + kq * 128 + kbl * 8;
  float4 a = ((const float4*)p)[0];
  float4 c = ((const float4*)p)[1];
  union { u16 s[8]; uint4 v; } o;
  o.s[0] = f2bf(a.x); o.s[1] = f2bf(a.y); o.s[2] = f2bf(a.z); o.s[3] = f2bf(a.w);
  o.s[4] = f2bf(c.x); o.s[5] = f2bf(c.y); o.s[6] = f2bf(c.z); o.s[7] = f2bf(c.w);

  const int cidx = (kbl << 4) | (ml ^ kbl);      // bank-spread slot
  *(uint4*)&ls[cidx * 8] = o.v;
  __syncthreads();

  const int g = (t & 0xF0) | ((t & 15) ^ ((t >> 4) & 15));
  uint4* dbase = (uint4*)(dst + (size_t)(mg * 512 + kq * 16) * 128);
  dbase[g] = ((const uint4*)ls)[t];
}

// ---------------------------------------------------------------------------
// Fused GEMM. vs R8, two changes:
// 1. PIPELINED GATHER: the B-gather for iter kt+1 is issued AFTER the MFMA
//    block of iter kt, into the SAME bfr registers -- the WAR dependency
//    (MFMAs read old bfr) pins the order, so next iter's MFMAs see ~200-cyc
//    old gathers instead of waiting the full ~150-cyc LDS latency that R8
//    exposed every iteration (gather was issued at loop top and immediately
//    consumed). MFMA loops j-outer so bfr[j] frees after 4 MFMAs, letting
//    the compiler interleave gather issue into the MFMA stream. idx loads
//    issued 3 iters ahead (2 reg sets), A loads 2 ahead (2 reg sets);
//    register count unchanged (~64 VGPR + 64 acc).
// 2. CENTROID CAST IN PROLOGUE: table cast fp32->bf16 here (reg-staged +
//    ds_write) instead of a separate cast kernel + DMA staging; one fewer
//    launch, centb buffer gone. 64 KB fp32 reads per block are L2-hot.
// Everything else identical to R8: 128x128 tile, 4 waves 2x2, barrier-free
// K-loop, XCD-aware remap (z = (id&7)>>1 pins each split-K chunk to an XCD
// pair; FETCH 37->12.6 MB measured), partials epilogue (NO atomics).
// ---------------------------------------------------------------------------
__global__ __launch_bounds__(256, 4) void gemm_fused_kernel(
    const u16* __restrict__ xs,     // x bf16, fragment-ordered [64][512][16][8]
    const float* __restrict__ cent, // [NCENT][8] fp32
    const int* __restrict__ assign, // [NBLKS*OUT_F] block-major
    const float* __restrict__ bias,
    float* __restrict__ out0,       // d_out (chunk s=0)
    float* __restrict__ partials) { // (SPLITK-1) x [NTOK][OUT_F]
  __shared__ __align__(16) u16 cs[NCENT * 8];   // 32 KB centroid table

  // XCD-aware remap (bijective over 1024 blocks)
  const int id = blockIdx.x;
  const int s = (id & 7) >> 1;             // z: one XCD pair per chunk
  const int tile = ((id >> 3) << 1) | (id & 1);
  const int n0 = (tile & 31) * 128;
  const int m0 = (tile >> 5) * 128;

  const int t = threadIdx.x;
  const int lane = t & 63;
  const int wv = t >> 6;
  const int wm = wv >> 1;
  const int wn = wv & 1;
  const int quad = lane >> 4;
  const int r16 = lane & 15;
  const int kb0 = (s * KCHUNK) >> 3;       // first quant block of this chunk

  // prologue: cast centroid table fp32 -> bf16 into LDS (8 centroids/thread)
  const float4* cf = (const float4*)cent;
#pragma unroll
  for (int it = 0; it < 8; ++it) {
    int c = it * 256 + t;
    float4 a = cf[(size_t)c * 2];
    float4 b = cf[(size_t)c * 2 + 1];
    union { u16 h[8]; uint4 v; } o;
    o.h[0] = f2bf(a.x); o.h[1] = f2bf(a.y); o.h[2] = f2bf(a.z); o.h[3] = f2bf(a.w);
    o.h[4] = f2bf(b.x); o.h[5] = f2bf(b.y); o.h[6] = f2bf(b.z); o.h[7] = f2bf(b.w);
    *(uint4*)&cs[(size_t)c * 8] = o.v;
  }

  floatx4 acc[4][4];
#pragma unroll
  for (int i = 0; i < 4; ++i)
#pragma unroll
    for (int j = 0; j < 4; ++j)
#pragma unroll
      for (int r = 0; r < 4; ++r) acc[i][j][r] = 0.0f;

  const int ncol = n0 + wn * 64 + r16;

  // A: uniform base (SGPR) + one per-lane u32 byte offset.
  const char* xA = (const char*)xs +
      ((size_t)((m0 >> 4) + wm * 4) * 512 + kb0) * 256;  // uniform
  const u32 va = (u32)(quad * 256 + r16 * 16);           // per-lane bytes
  // idx: uniform base + one per-lane u32 element offset
  const int* ai = assign + (size_t)kb0 * OUT_F;          // uniform
  const u32 vi = (u32)(quad * OUT_F + ncol);             // per-lane elems

  // prologue loads: idx[0] (for gather0), idx[1], idx[2]; A[0], A[1]
  int idx0[4], idxc[4], idxn[4];
#pragma unroll
  for (int j = 0; j < 4; ++j) idx0[j] = ai[vi + (u32)(j * 16)];
  short8 afc[4], afn[4];
#pragma unroll
  for (int i = 0; i < 4; ++i)
    afc[i] = *(const short8*)(xA + (va + (u32)i * 131072u));
#pragma unroll
  for (int i = 0; i < 4; ++i)
    afn[i] = *(const short8*)(xA + (va + 1024u + (u32)i * 131072u));
#pragma unroll
  for (int j = 0; j < 4; ++j) idxc[j] = ai[(size_t)4 * OUT_F + vi + (u32)(j * 16)];
#pragma unroll
  for (int j = 0; j < 4; ++j) idxn[j] = ai[(size_t)8 * OUT_F + vi + (u32)(j * 16)];

  __syncthreads();   // centroid table ready (single barrier of the kernel)

  const short8* csv = (const short8*)cs;
  short8 bfr[4];
#pragma unroll
  for (int j = 0; j < 4; ++j) bfr[j] = csv[idx0[j]];   // gather[0]

  for (int kt = 0; kt < KITERS; ++kt) {
    // MFMA on (A[kt], B[kt]); j-outer so bfr[j] frees after its 4 MFMAs
#pragma unroll
    for (int j = 0; j < 4; ++j)
#pragma unroll
      for (int i = 0; i < 4; ++i)
        acc[i][j] = __builtin_amdgcn_mfma_f32_16x16x32_bf16(afc[i], bfr[j], acc[i][j], 0, 0, 0);

    // gather B[kt+1] into the same bfr regs (WAR pins this after the MFMAs)
    if (kt + 1 < KITERS) {
#pragma unroll
      for (int j = 0; j < 4; ++j) bfr[j] = csv[idxc[j]];
    }
    // rotate idx; issue idx[kt+3]
#pragma unroll
    for (int j = 0; j < 4; ++j) idxc[j] = idxn[j];
    if (kt + 3 < KITERS) {
      const int* an = ai + (size_t)(kt + 3) * 4 * OUT_F;
#pragma unroll
      for (int j = 0; j < 4; ++j) idxn[j] = an[vi + (u32)(j * 16)];
    }
    // rotate A; issue A[kt+2]
#pragma unroll
    for (int i = 0; i < 4; ++i) afc[i] = afn[i];
    if (kt + 2 < KITERS) {
      const char* xk = xA + (va + (u32)((kt + 2) * 1024));
#pragma unroll
      for (int i = 0; i < 4; ++i)
        afn[i] = *(const short8*)(xk + (u32)i * 131072u);
    }
  }

  // epilogue: C/D layout col = lane&15 (+j*16), row = quad*4 + reg (+i*16)
  float* C = (s == 0) ? out0 : (partials + (size_t)(s - 1) * NTOK * OUT_F);
  const int row_base = m0 + wm * 64 + quad * 4;
#pragma unroll
  for (int j = 0; j < 4; ++j) {
    const int col = ncol + j * 16;
#pragma unroll
    for (int i = 0; i < 4; ++i) {
      const int row = row_base + i * 16;
#pragma unroll
      for (int r = 0; r < 4; ++r)
        C[(size_t)(row + r) * OUT_F + col] = acc[i][j][r];
    }
  }
}

// ---------------------------------------------------------------------------
// reduce: out += sum(partials) + bias   (float4 per thread)
// ---------------------------------------------------------------------------
__global__ __launch_bounds__(256) void reduce_kernel(
    float* __restrict__ out, const float* __restrict__ partials,
    const float* __restrict__ bias, int sm1) {
  int g = blockIdx.x * 256 + threadIdx.x;  // float4 index over [NTOK*OUT_F/4]
  float4 v = ((const float4*)out)[g];
  for (int s = 0; s < sm1; ++s) {
    float4 p = ((const float4*)(partials + (size_t)s * NTOK * OUT_F))[g];
    v.x += p.x; v.y += p.y; v.z += p.z; v.w += p.w;
  }
  float4 b = ((const float4*)bias)[g & (OUT_F / 4 - 1)];
  v.x += b.x; v.y += b.y; v.z += b.z; v.w += b.w;
  ((float4*)out)[g] = v;
}

extern "C" void kernel_launch(void* const* d_in, const int* in_sizes, int n_in,
                              void* d_out, int out_size, void* d_ws, size_t ws_size,
                              hipStream_t stream) {
  const float* x      = (const float*)d_in[0];  // [1024][4096] fp32
  const float* cent   = (const float*)d_in[1];  // [2048][8] fp32
  const float* bias   = (const float*)d_in[2];  // [4096] fp32
  const int*   assign = (const int*)d_in[3];    // [512*4096] int32
  float* out = (float*)d_out;

  // ws layout: xs (8 MB) | partials (SPLITK-1)*16 MB
  const size_t xb_bytes = (size_t)NTOK * IN_F * sizeof(u16);      // 8388608
  u16*   xs       = (u16*)d_ws;
  float* partials = (float*)((char*)d_ws + xb_bytes);

  hipLaunchKernelGGL(cast_swz_kernel, dim3(64 * 32), dim3(256), 0, stream, x, xs);
  hipLaunchKernelGGL(gemm_fused_kernel, dim3(1024), dim3(256), 0, stream,
                     xs, cent, assign, bias, out, partials);
  hipLaunchKernelGGL(reduce_kernel, dim3((NTOK * OUT_F / 4) / 256), dim3(256), 0, stream,
                     out, partials, bias, SPLITK - 1);
}

// Round 10
// 135.986 us; speedup vs baseline: 1.1071x; 1.1071x over previous
//
#include <hip/hip_runtime.h>
#include <hip/hip_bf16.h>

#define IN_F   4096
#define OUT_F  4096
#define QBLK   8
#define NBLKS  512
#define NTOK   1024
#define NCENT  2048

#define SPLITK 4
#define KCHUNK (IN_F / SPLITK)   // 1024
#define KITERS (KCHUNK / 32)     // 32

typedef unsigned int u32;
typedef unsigned short u16;
typedef __attribute__((ext_vector_type(8))) short short8;   // 8 bf16 (MFMA A/B frag)
typedef __attribute__((ext_vector_type(4))) float floatx4;  // MFMA C/D frag

// round-to-nearest-even fp32 -> bf16
__device__ __forceinline__ u16 f2bf(float f) {
  union { float f; u32 u; } v; v.f = f;
  u32 u = v.u;
  return (u16)((u + 0x7fffu + ((u >> 16) & 1u)) >> 16);
}

__device__ __forceinline__ void load_lds_16(const void* g, void* l) {
  __builtin_amdgcn_global_load_lds(
      (const __attribute__((address_space(1))) u32*)g,
      (__attribute__((address_space(3))) u32*)l, 16, 0, 0);
}

// ---------------------------------------------------------------------------
// cast fp32 -> bf16 (plain layout) -- used for centroids only
// ---------------------------------------------------------------------------
__global__ __launch_bounds__(256) void cast_bf16_kernel(
    const float* __restrict__ src, u16* __restrict__ dst) {
  int g = blockIdx.x * 256 + threadIdx.x;   // one 8-element chunk
  const float4* sv = (const float4*)src;
  float4 a = sv[(size_t)g * 2];
  float4 b = sv[(size_t)g * 2 + 1];
  union { u16 s[8]; uint4 v; } o;
  o.s[0] = f2bf(a.x); o.s[1] = f2bf(a.y); o.s[2] = f2bf(a.z); o.s[3] = f2bf(a.w);
  o.s[4] = f2bf(b.x); o.s[5] = f2bf(b.y); o.s[6] = f2bf(b.z); o.s[7] = f2bf(b.w);
  ((uint4*)dst)[g] = o.v;
}

// ---------------------------------------------------------------------------
// cast x fp32 -> bf16 in MFMA-fragment-ordered layout:
//   elem (m,k) -> [(m>>4)*512 + (k>>3)]*128 + (m&15)*8 + (k&7)
// A wave's A-fragment load becomes ONE contiguous 1 KB global_load_dwordx4.
// ---------------------------------------------------------------------------
__global__ __launch_bounds__(256) void cast_swz_kernel(
    const float* __restrict__ src, u16* __restrict__ dst) {
  __shared__ __align__(16) u16 ls[256 * 8];      // 256 chunks of 16 B = 4 KB
  const int b = blockIdx.x;
  const int mg = b >> 5;          // m-group 0..63
  const int kq = b & 31;          // k-chunk of 128 elems, 0..31
  const int t = threadIdx.x;
  const int ml = t >> 4;          // m within group 0..15
  const int kbl = t & 15;         // quant block within chunk 0..15

  const float* p = src + (size_t)(mg * 16 + ml) * IN_F + kq * 128 + kbl * 8;
  float4 a = ((const float4*)p)[0];
  float4 c = ((const float4*)p)[1];
  union { u16 s[8]; uint4 v; } o;
  o.s[0] = f2bf(a.x); o.s[1] = f2bf(a.y); o.s[2] = f2bf(a.z); o.s[3] = f2bf(a.w);
  o.s[4] = f2bf(c.x); o.s[5] = f2bf(c.y); o.s[6] = f2bf(c.z); o.s[7] = f2bf(c.w);

  const int cidx = (kbl << 4) | (ml ^ kbl);      // bank-spread slot
  *(uint4*)&ls[cidx * 8] = o.v;
  __syncthreads();

  const int g = (t & 0xF0) | ((t & 15) ^ ((t >> 4) & 15));
  uint4* dbase = (uint4*)(dst + (size_t)(mg * 512 + kq * 16) * 128);
  dbase[g] = ((const uint4*)ls)[t];
}

// ---------------------------------------------------------------------------
// Fused GEMM. ONE change vs R8: 8 WAVES PER BLOCK (2 wm x 4 wn), same
// 128x128 tile. Each wave owns 64x32 (4x2 of mfma_f32_16x16x32_bf16), so
// per-thread state drops to 32 acc AGPR + ~60 VGPR < 102 -> 5 waves/SIMD
// resident (launch_bounds(512,5)) vs R8's 2.3 -- pure TLP to hide the
// A-frag (~200-400 cyc L2) and B-gather (~150 cyc LDS) latency that R8's
// counters showed exposed (all pipes <40%, occupancy 29%). Per-block
// B-gather count unchanged (16/iter, wm-pair duplication); A-frag reads
// duplicated 4x across wn-waves but L1-served. Loop body, prefetch depth,
// DMA centroid staging, XCD remap (z=(id&7)>>1: FETCH 37->12.6 MB
// measured), and partials epilogue are R8 verbatim (R9's reorder +
// prologue-cast both regressed and are reverted).
//   C[m][n] = sum_k x[m][k] * centroids[assign[(k/8)*OUT_F+n]][k%8]
// ---------------------------------------------------------------------------
__global__ __launch_bounds__(512, 5) void gemm_fused_kernel(
    const u16* __restrict__ xs,     // x bf16, fragment-ordered [64][512][16][8]
    const u16* __restrict__ centb,  // [NCENT][8] bf16
    const int* __restrict__ assign, // [NBLKS*OUT_F] block-major
    const float* __restrict__ bias,
    float* __restrict__ out0,       // d_out (chunk s=0)
    float* __restrict__ partials) { // (SPLITK-1) x [NTOK][OUT_F]
  __shared__ __align__(16) u16 cs[NCENT * 8];   // 32 KB centroid table

  // XCD-aware remap (bijective over 1024 blocks)
  const int id = blockIdx.x;
  const int s = (id & 7) >> 1;             // z: one XCD pair per chunk
  const int tile = ((id >> 3) << 1) | (id & 1);
  const int n0 = (tile & 31) * 128;
  const int m0 = (tile >> 5) * 128;

  const int t = threadIdx.x;
  const int lane = t & 63;
  const int wv = t >> 6;                   // 0..7
  const int wm = wv >> 2;                  // 0..1 (row half)
  const int wn = wv & 3;                   // 0..3 (col quarter)
  const int quad = lane >> 4;
  const int r16 = lane & 15;
  const int kb0 = (s * KCHUNK) >> 3;       // first quant block of this chunk

  // stage centroid table: 2048 chunks of 16B = 4 per thread (DMA, no VGPR)
#pragma unroll
  for (int it = 0; it < 4; ++it) {
    int c = it * 512 + t;
    load_lds_16(centb + (size_t)c * 8, cs + (size_t)c * 8);
  }

  floatx4 acc[4][2];
#pragma unroll
  for (int i = 0; i < 4; ++i)
#pragma unroll
    for (int j = 0; j < 2; ++j)
#pragma unroll
      for (int r = 0; r < 4; ++r) acc[i][j][r] = 0.0f;

  const int ncol = n0 + wn * 32 + r16;

  // A: uniform base (SGPR) + one per-lane u32 byte offset.
  const char* xA = (const char*)xs +
      ((size_t)((m0 >> 4) + wm * 4) * 512 + kb0) * 256;  // uniform
  const u32 va = (u32)(quad * 256 + r16 * 16);           // per-lane bytes
  // idx: uniform base + one per-lane u32 element offset
  const int* ai = assign + (size_t)kb0 * OUT_F;          // uniform
  const u32 vi = (u32)(quad * OUT_F + ncol);             // per-lane elems

  // prologue: load iter-0 A frags + indices
  short8 afc[4];
  int idxc[2];
#pragma unroll
  for (int i = 0; i < 4; ++i)
    afc[i] = *(const short8*)(xA + (va + (u32)i * 131072u));
#pragma unroll
  for (int j = 0; j < 2; ++j) idxc[j] = ai[vi + (u32)(j * 16)];

  __syncthreads();   // centroid table ready (single barrier of the kernel)

  const short8* csv = (const short8*)cs;
#pragma unroll 2
  for (int kt = 0; kt < KITERS; ++kt) {
    // prefetch next iteration's A frags + indices (uniform guard)
    short8 afn[4];
    int idxn[2];
    if (kt + 1 < KITERS) {
      const char* xk = xA + (va + (u32)((kt + 1) * 1024));
#pragma unroll
      for (int i = 0; i < 4; ++i)
        afn[i] = *(const short8*)(xk + (u32)i * 131072u);
      const int* an = ai + (size_t)(kt + 1) * 4 * OUT_F;
#pragma unroll
      for (int j = 0; j < 2; ++j) idxn[j] = an[vi + (u32)(j * 16)];
    }

    // gather B frags from LDS table (one 16 B lookup per lane per frag)
    short8 bfr[2];
#pragma unroll
    for (int j = 0; j < 2; ++j) bfr[j] = csv[idxc[j]];

#pragma unroll
    for (int i = 0; i < 4; ++i)
#pragma unroll
      for (int j = 0; j < 2; ++j)
        acc[i][j] = __builtin_amdgcn_mfma_f32_16x16x32_bf16(afc[i], bfr[j], acc[i][j], 0, 0, 0);

#pragma unroll
    for (int i = 0; i < 4; ++i) afc[i] = afn[i];
#pragma unroll
    for (int j = 0; j < 2; ++j) idxc[j] = idxn[j];
  }

  // epilogue: C/D layout col = lane&15 (+j*16), row = quad*4 + reg (+i*16)
  float* C = (s == 0) ? out0 : (partials + (size_t)(s - 1) * NTOK * OUT_F);
  const int row_base = m0 + wm * 64 + quad * 4;
#pragma unroll
  for (int j = 0; j < 2; ++j) {
    const int col = ncol + j * 16;
#pragma unroll
    for (int i = 0; i < 4; ++i) {
      const int row = row_base + i * 16;
#pragma unroll
      for (int r = 0; r < 4; ++r)
        C[(size_t)(row + r) * OUT_F + col] = acc[i][j][r];
    }
  }
}

// ---------------------------------------------------------------------------
// reduce: out += sum(partials) + bias   (float4 per thread)
// ---------------------------------------------------------------------------
__global__ __launch_bounds__(256) void reduce_kernel(
    float* __restrict__ out, const float* __restrict__ partials,
    const float* __restrict__ bias, int sm1) {
  int g = blockIdx.x * 256 + threadIdx.x;  // float4 index over [NTOK*OUT_F/4]
  float4 v = ((const float4*)out)[g];
  for (int s = 0; s < sm1; ++s) {
    float4 p = ((const float4*)(partials + (size_t)s * NTOK * OUT_F))[g];
    v.x += p.x; v.y += p.y; v.z += p.z; v.w += p.w;
  }
  float4 b = ((const float4*)bias)[g & (OUT_F / 4 - 1)];
  v.x += b.x; v.y += b.y; v.z += b.z; v.w += b.w;
  ((float4*)out)[g] = v;
}

extern "C" void kernel_launch(void* const* d_in, const int* in_sizes, int n_in,
                              void* d_out, int out_size, void* d_ws, size_t ws_size,
                              hipStream_t stream) {
  const float* x      = (const float*)d_in[0];  // [1024][4096] fp32
  const float* cent   = (const float*)d_in[1];  // [2048][8] fp32
  const float* bias   = (const float*)d_in[2];  // [4096] fp32
  const int*   assign = (const int*)d_in[3];    // [512*4096] int32
  float* out = (float*)d_out;

  // ws layout: xs (8 MB) | centb (32 KB) | partials (SPLITK-1)*16 MB
  const size_t xb_bytes   = (size_t)NTOK * IN_F * sizeof(u16);      // 8388608
  const size_t cent_bytes = (size_t)NCENT * 8 * sizeof(u16);        // 32768
  u16*   xs       = (u16*)d_ws;
  u16*   centb    = (u16*)((char*)d_ws + xb_bytes);
  float* partials = (float*)((char*)d_ws + xb_bytes + cent_bytes);

  hipLaunchKernelGGL(cast_swz_kernel, dim3(64 * 32), dim3(256), 0, stream, x, xs);
  hipLaunchKernelGGL(cast_bf16_kernel, dim3((NCENT * 8 / 8) / 256), dim3(256), 0, stream,
                     cent, centb);
  hipLaunchKernelGGL(gemm_fused_kernel, dim3(1024), dim3(512), 0, stream,
                     xs, centb, assign, bias, out, partials);
  hipLaunchKernelGGL(reduce_kernel, dim3((NTOK * OUT_F / 4) / 256), dim3(256), 0, stream,
                     out, partials, bias, SPLITK - 1);
}

// Round 11
// 117.284 us; speedup vs baseline: 1.2837x; 1.1595x over previous
//
#include <hip/hip_runtime.h>
#include <hip/hip_bf16.h>

#define IN_F   4096
#define OUT_F  4096
#define QBLK   8
#define NBLKS  512
#define NTOK   1024
#define NCENT  2048

#define SPLITK 4
#define KCHUNK (IN_F / SPLITK)   // 1024
#define KITERS (KCHUNK / 32)     // 32

typedef unsigned int u32;
typedef unsigned short u16;
typedef __attribute__((ext_vector_type(8))) short short8;   // 8 bf16 (MFMA A/B frag)
typedef __attribute__((ext_vector_type(4))) float floatx4;  // MFMA C/D frag

// round-to-nearest-even fp32 -> bf16
__device__ __forceinline__ u16 f2bf(float f) {
  union { float f; u32 u; } v; v.f = f;
  u32 u = v.u;
  return (u16)((u + 0x7fffu + ((u >> 16) & 1u)) >> 16);
}

__device__ __forceinline__ void load_lds_16(const void* g, void* l) {
  __builtin_amdgcn_global_load_lds(
      (const __attribute__((address_space(1))) u32*)g,
      (__attribute__((address_space(3))) u32*)l, 16, 0, 0);
}

// ---------------------------------------------------------------------------
// cast fp32 -> bf16 (plain layout) -- used for centroids only
// ---------------------------------------------------------------------------
__global__ __launch_bounds__(256) void cast_bf16_kernel(
    const float* __restrict__ src, u16* __restrict__ dst) {
  int g = blockIdx.x * 256 + threadIdx.x;   // one 8-element chunk
  const float4* sv = (const float4*)src;
  float4 a = sv[(size_t)g * 2];
  float4 b = sv[(size_t)g * 2 + 1];
  union { u16 s[8]; uint4 v; } o;
  o.s[0] = f2bf(a.x); o.s[1] = f2bf(a.y); o.s[2] = f2bf(a.z); o.s[3] = f2bf(a.w);
  o.s[4] = f2bf(b.x); o.s[5] = f2bf(b.y); o.s[6] = f2bf(b.z); o.s[7] = f2bf(b.w);
  ((uint4*)dst)[g] = o.v;
}

// ---------------------------------------------------------------------------
// cast x fp32 -> bf16 in MFMA-fragment-ordered layout:
//   elem (m,k) -> [(m>>4)*512 + (k>>3)]*128 + (m&15)*8 + (k&7)
// A wave's A-fragment load becomes ONE contiguous 1 KB global_load_dwordx4.
// ---------------------------------------------------------------------------
__global__ __launch_bounds__(256) void cast_swz_kernel(
    const float* __restrict__ src, u16* __restrict__ dst) {
  __shared__ __align__(16) u16 ls[256 * 8];      // 256 chunks of 16 B = 4 KB
  const int b = blockIdx.x;
  const int mg = b >> 5;          // m-group 0..63
  const int kq = b & 31;          // k-chunk of 128 elems, 0..31
  const int t = threadIdx.x;
  const int ml = t >> 4;          // m within group 0..15
  const int kbl = t & 15;         // quant block within chunk 0..15

  const float* p = src + (size_t)(mg * 16 + ml) * IN_F + kq * 128 + kbl * 8;
  float4 a = ((const float4*)p)[0];
  float4 c = ((const float4*)p)[1];
  union { u16 s[8]; uint4 v; } o;
  o.s[0] = f2bf(a.x); o.s[1] = f2bf(a.y); o.s[2] = f2bf(a.z); o.s[3] = f2bf(a.w);
  o.s[4] = f2bf(c.x); o.s[5] = f2bf(c.y); o.s[6] = f2bf(c.z); o.s[7] = f2bf(c.w);

  const int cidx = (kbl << 4) | (ml ^ kbl);      // bank-spread slot
  *(uint4*)&ls[cidx * 8] = o.v;
  __syncthreads();

  const int g = (t & 0xF0) | ((t & 15) ^ ((t >> 4) & 15));
  uint4* dbase = (uint4*)(dst + (size_t)(mg * 512 + kq * 16) * 128);
  dbase[g] = ((const uint4*)ls)[t];
}

// ---------------------------------------------------------------------------
// Fused GEMM with ON-CHIP SPLIT-K. One block = one 128x128 output tile,
// 16 waves = 4 K-chunk groups x (2x2 waves). Each group runs R8's
// barrier-free K-loop VERBATIM over its own 1024-K chunk (s = wv>>2
// replaces blockIdx.z). Epilogue: groups 0..3 sum accumulators through a
// padded LDS buffer (Cs[128][132], quad rows land 16 banks apart -> only
// free 2-way conflicts), then all threads add bias and store float4.
// DELETES: partials buffer (48 MB writes), reduce kernel (80 MB traffic,
// ~15 us), one launch. Summation order (s0+s1+s2+s3) identical to the old
// reduce -> bitwise-same output.
// Grid 256 = 1 block/CU exactly; 16 waves/CU co-resident (4/SIMD, forced
// by launch_bounds(1024,4) -> regs <= 128, which R8's loop fits: 64 VGPR +
// 64 acc). Swizzle m0=(id&7)*128: each XCD owns one m-band, so its 1 MB
// x-slice is L2-resident; assign slices stream once, L3-shared cross-XCD.
//   C[m][n] = sum_k x[m][k] * centroids[assign[(k/8)*OUT_F+n]][k%8] + bias
// ---------------------------------------------------------------------------
__global__ __launch_bounds__(1024, 4) void gemm_fused_kernel(
    const u16* __restrict__ xs,     // x bf16, fragment-ordered [64][512][16][8]
    const u16* __restrict__ centb,  // [NCENT][8] bf16
    const int* __restrict__ assign, // [NBLKS*OUT_F] block-major
    const float* __restrict__ bias,
    float* __restrict__ out) {      // [NTOK][OUT_F]
  __shared__ __align__(16) u16 cs[NCENT * 8];     // 32 KB centroid table
  __shared__ __align__(16) float Cs[128 * 132];   // 67.6 KB reduce buffer

  // XCD swizzle: id%8 = XCD under linear round-robin dispatch
  const int id = blockIdx.x;
  const int m0 = (id & 7) * 128;    // one m-band per XCD
  const int n0 = (id >> 3) * 128;

  const int t = threadIdx.x;
  const int lane = t & 63;
  const int wv = t >> 6;            // 0..15
  const int s = wv >> 2;            // K-chunk group 0..3
  const int wq = wv & 3;
  const int wm = wq >> 1;
  const int wn = wq & 1;
  const int quad = lane >> 4;
  const int r16 = lane & 15;
  const int kb0 = s * (KCHUNK >> 3);       // first quant block of this chunk

  // stage centroid table: 2048 chunks of 16B = 2 per thread (DMA, no VGPR)
#pragma unroll
  for (int it = 0; it < 2; ++it) {
    int c = it * 1024 + t;
    load_lds_16(centb + (size_t)c * 8, cs + (size_t)c * 8);
  }

  floatx4 acc[4][4];
#pragma unroll
  for (int i = 0; i < 4; ++i)
#pragma unroll
    for (int j = 0; j < 4; ++j)
#pragma unroll
      for (int r = 0; r < 4; ++r) acc[i][j][r] = 0.0f;

  const int ncol = n0 + wn * 64 + r16;

  // A: uniform base (SGPR) + one per-lane u32 byte offset (R8 verbatim)
  const char* xA = (const char*)xs +
      ((size_t)((m0 >> 4) + wm * 4) * 512 + kb0) * 256;  // uniform
  const u32 va = (u32)(quad * 256 + r16 * 16);           // per-lane bytes
  const int* ai = assign + (size_t)kb0 * OUT_F;          // uniform
  const u32 vi = (u32)(quad * OUT_F + ncol);             // per-lane elems

  // prologue: load iter-0 A frags + indices
  short8 afc[4];
  int idxc[4];
#pragma unroll
  for (int i = 0; i < 4; ++i)
    afc[i] = *(const short8*)(xA + (va + (u32)i * 131072u));
#pragma unroll
  for (int j = 0; j < 4; ++j) idxc[j] = ai[vi + (u32)(j * 16)];

  __syncthreads();   // centroid table ready

  const short8* csv = (const short8*)cs;
#pragma unroll 2
  for (int kt = 0; kt < KITERS; ++kt) {
    // prefetch next iteration's A frags + indices (uniform guard)
    short8 afn[4];
    int idxn[4];
    if (kt + 1 < KITERS) {
      const char* xk = xA + (va + (u32)((kt + 1) * 1024));
#pragma unroll
      for (int i = 0; i < 4; ++i)
        afn[i] = *(const short8*)(xk + (u32)i * 131072u);
      const int* an = ai + (size_t)(kt + 1) * 4 * OUT_F;
#pragma unroll
      for (int j = 0; j < 4; ++j) idxn[j] = an[vi + (u32)(j * 16)];
    }

    // gather B frags from LDS table (one 16 B lookup per lane per frag)
    short8 bfr[4];
#pragma unroll
    for (int j = 0; j < 4; ++j) bfr[j] = csv[idxc[j]];

#pragma unroll
    for (int i = 0; i < 4; ++i)
#pragma unroll
      for (int j = 0; j < 4; ++j)
        acc[i][j] = __builtin_amdgcn_mfma_f32_16x16x32_bf16(afc[i], bfr[j], acc[i][j], 0, 0, 0);

#pragma unroll
    for (int i = 0; i < 4; ++i) afc[i] = afn[i];
#pragma unroll
    for (int j = 0; j < 4; ++j) idxc[j] = idxn[j];
  }

  // ---- on-chip split-K reduction through LDS ----
  // C/D layout: col = cbase + j*16, row = rbase + i*16 + r
  const int rbase = wm * 64 + quad * 4;
  const int cbase = wn * 64 + r16;
  if (s == 0) {
#pragma unroll
    for (int i = 0; i < 4; ++i)
#pragma unroll
      for (int j = 0; j < 4; ++j)
#pragma unroll
        for (int r = 0; r < 4; ++r)
          Cs[(rbase + i * 16 + r) * 132 + cbase + j * 16] = acc[i][j][r];
  }
  __syncthreads();
#pragma unroll
  for (int g = 1; g < 4; ++g) {
    if (s == g) {
#pragma unroll
      for (int i = 0; i < 4; ++i)
#pragma unroll
        for (int j = 0; j < 4; ++j)
#pragma unroll
          for (int r = 0; r < 4; ++r)
            Cs[(rbase + i * 16 + r) * 132 + cbase + j * 16] += acc[i][j][r];
    }
    __syncthreads();
  }

  // cooperative store: 4 passes x (32 rows x 32 float4), bias fused
  const int c4 = t & 31;
  const float4 b4 = ((const float4*)bias)[(n0 >> 2) + c4];
#pragma unroll
  for (int p = 0; p < 4; ++p) {
    const int rr = p * 32 + (t >> 5);
    float4 v = *(const float4*)&Cs[rr * 132 + c4 * 4];
    v.x += b4.x; v.y += b4.y; v.z += b4.z; v.w += b4.w;
    ((float4*)out)[(((size_t)(m0 + rr) * OUT_F + n0) >> 2) + c4] = v;
  }
}

extern "C" void kernel_launch(void* const* d_in, const int* in_sizes, int n_in,
                              void* d_out, int out_size, void* d_ws, size_t ws_size,
                              hipStream_t stream) {
  const float* x      = (const float*)d_in[0];  // [1024][4096] fp32
  const float* cent   = (const float*)d_in[1];  // [2048][8] fp32
  const float* bias   = (const float*)d_in[2];  // [4096] fp32
  const int*   assign = (const int*)d_in[3];    // [512*4096] int32
  float* out = (float*)d_out;

  // ws layout: xs (8 MB) | centb (32 KB)   -- no partials (on-chip reduce)
  const size_t xb_bytes = (size_t)NTOK * IN_F * sizeof(u16);      // 8388608
  u16* xs    = (u16*)d_ws;
  u16* centb = (u16*)((char*)d_ws + xb_bytes);

  hipLaunchKernelGGL(cast_swz_kernel, dim3(64 * 32), dim3(256), 0, stream, x, xs);
  hipLaunchKernelGGL(cast_bf16_kernel, dim3((NCENT * 8 / 8) / 256), dim3(256), 0, stream,
                     cent, centb);
  hipLaunchKernelGGL(gemm_fused_kernel, dim3(256), dim3(1024), 0, stream,
                     xs, centb, assign, bias, out);
}

// Round 12
// 116.862 us; speedup vs baseline: 1.2883x; 1.0036x over previous
//
#include <hip/hip_runtime.h>
#include <hip/hip_bf16.h>

#define IN_F   4096
#define OUT_F  4096
#define QBLK   8
#define NBLKS  512
#define NTOK   1024
#define NCENT  2048

#define SPLITK 4
#define KCHUNK (IN_F / SPLITK)   // 1024
#define KITERS (KCHUNK / 32)     // 32

typedef unsigned int u32;
typedef unsigned short u16;
typedef __attribute__((ext_vector_type(8))) short short8;   // 8 bf16 (MFMA A/B frag)
typedef __attribute__((ext_vector_type(4))) float floatx4;  // MFMA C/D frag

// round-to-nearest-even fp32 -> bf16
__device__ __forceinline__ u16 f2bf(float f) {
  union { float f; u32 u; } v; v.f = f;
  u32 u = v.u;
  return (u16)((u + 0x7fffu + ((u >> 16) & 1u)) >> 16);
}

__device__ __forceinline__ void load_lds_16(const void* g, void* l) {
  __builtin_amdgcn_global_load_lds(
      (const __attribute__((address_space(1))) u32*)g,
      (__attribute__((address_space(3))) u32*)l, 16, 0, 0);
}

// ---------------------------------------------------------------------------
// cast fp32 -> bf16 (plain layout) -- used for centroids only
// ---------------------------------------------------------------------------
__global__ __launch_bounds__(256) void cast_bf16_kernel(
    const float* __restrict__ src, u16* __restrict__ dst) {
  int g = blockIdx.x * 256 + threadIdx.x;   // one 8-element chunk
  const float4* sv = (const float4*)src;
  float4 a = sv[(size_t)g * 2];
  float4 b = sv[(size_t)g * 2 + 1];
  union { u16 s[8]; uint4 v; } o;
  o.s[0] = f2bf(a.x); o.s[1] = f2bf(a.y); o.s[2] = f2bf(a.z); o.s[3] = f2bf(a.w);
  o.s[4] = f2bf(b.x); o.s[5] = f2bf(b.y); o.s[6] = f2bf(b.z); o.s[7] = f2bf(b.w);
  ((uint4*)dst)[g] = o.v;
}

// ---------------------------------------------------------------------------
// cast x fp32 -> bf16 in MFMA-fragment-ordered layout:
//   elem (m,k) -> [(m>>4)*512 + (k>>3)]*128 + (m&15)*8 + (k&7)
// A wave's A-fragment load becomes ONE contiguous 1 KB global_load_dwordx4.
// ---------------------------------------------------------------------------
__global__ __launch_bounds__(256) void cast_swz_kernel(
    const float* __restrict__ src, u16* __restrict__ dst) {
  __shared__ __align__(16) u16 ls[256 * 8];      // 256 chunks of 16 B = 4 KB
  const int b = blockIdx.x;
  const int mg = b >> 5;          // m-group 0..63
  const int kq = b & 31;          // k-chunk of 128 elems, 0..31
  const int t = threadIdx.x;
  const int ml = t >> 4;          // m within group 0..15
  const int kbl = t & 15;         // quant block within chunk 0..15

  const float* p = src + (size_t)(mg * 16 + ml) * IN_F + kq * 128 + kbl * 8;
  float4 a = ((const float4*)p)[0];
  float4 c = ((const float4*)p)[1];
  union { u16 s[8]; uint4 v; } o;
  o.s[0] = f2bf(a.x); o.s[1] = f2bf(a.y); o.s[2] = f2bf(a.z); o.s[3] = f2bf(a.w);
  o.s[4] = f2bf(c.x); o.s[5] = f2bf(c.y); o.s[6] = f2bf(c.z); o.s[7] = f2bf(c.w);

  const int cidx = (kbl << 4) | (ml ^ kbl);      // bank-spread slot
  *(uint4*)&ls[cidx * 8] = o.v;
  __syncthreads();

  const int g = (t & 0xF0) | ((t & 15) ^ ((t >> 4) & 15));
  uint4* dbase = (uint4*)(dst + (size_t)(mg * 512 + kq * 16) * 128);
  dbase[g] = ((const uint4*)ls)[t];
}

// ---------------------------------------------------------------------------
// Fused GEMM, on-chip split-K, 2 BLOCKS PER CU (vs R11's one 16-wave block).
// One block = one 128x64 output tile, 8 waves = 4 K-chunk groups x 2
// wm-waves; each wave runs the proven 64x64 acc[4][4] K-loop verbatim over
// its group's 1024-K chunk (wn eliminated; cols = n0 + r16 + j*16).
// LDS 66.8 KB/block (32K table + 128x68 padded Cs) -> 2 blocks co-resident
// per CU (133.6 KB, regs 128 -> still 16 waves/CU): same per-CU LDS/L1/MFMA
// demand, but the two blocks' K-loops and epilogues interleave (one block's
// reduce barriers overlap the other's gathers -- the m114 wave-overlap
// mechanism at block scope), grid 512 halves tail granularity, and the
// serial 4-step LDS reduce covers half the tile.
// Epilogue: groups 0..3 sum accumulators through Cs (quad rows 16 banks
// apart -> free 2-way), then cooperative bias+float4 store. No partials, no
// reduce kernel. Summation order s0+s1+s2+s3 identical -> bitwise-same.
// XCD swizzle: id&7 = m-band (1 MB x-slice L2-resident per XCD).
//   C[m][n] = sum_k x[m][k] * centroids[assign[(k/8)*OUT_F+n]][k%8] + bias
// ---------------------------------------------------------------------------
__global__ __launch_bounds__(512, 4) void gemm_fused_kernel(
    const u16* __restrict__ xs,     // x bf16, fragment-ordered [64][512][16][8]
    const u16* __restrict__ centb,  // [NCENT][8] bf16
    const int* __restrict__ assign, // [NBLKS*OUT_F] block-major
    const float* __restrict__ bias,
    float* __restrict__ out) {      // [NTOK][OUT_F]
  __shared__ __align__(16) u16 cs[NCENT * 8];    // 32 KB centroid table
  __shared__ __align__(16) float Cs[128 * 68];   // 34.8 KB reduce buffer

  // XCD swizzle: id%8 = XCD under linear round-robin dispatch
  const int id = blockIdx.x;
  const int m0 = (id & 7) * 128;    // one m-band per XCD
  const int n0 = (id >> 3) * 64;    // 64 n-tiles

  const int t = threadIdx.x;
  const int lane = t & 63;
  const int wv = t >> 6;            // 0..7
  const int s = wv >> 1;            // K-chunk group 0..3
  const int wm = wv & 1;            // row half
  const int quad = lane >> 4;
  const int r16 = lane & 15;
  const int kb0 = s * (KCHUNK >> 3);       // first quant block of this chunk

  // stage centroid table: 2048 chunks of 16B = 4 per thread (DMA, no VGPR)
#pragma unroll
  for (int it = 0; it < 4; ++it) {
    int c = it * 512 + t;
    load_lds_16(centb + (size_t)c * 8, cs + (size_t)c * 8);
  }

  floatx4 acc[4][4];
#pragma unroll
  for (int i = 0; i < 4; ++i)
#pragma unroll
    for (int j = 0; j < 4; ++j)
#pragma unroll
      for (int r = 0; r < 4; ++r) acc[i][j][r] = 0.0f;

  const int ncol = n0 + r16;

  // A: uniform base (SGPR) + one per-lane u32 byte offset (proven loop)
  const char* xA = (const char*)xs +
      ((size_t)((m0 >> 4) + wm * 4) * 512 + kb0) * 256;  // uniform
  const u32 va = (u32)(quad * 256 + r16 * 16);           // per-lane bytes
  const int* ai = assign + (size_t)kb0 * OUT_F;          // uniform
  const u32 vi = (u32)(quad * OUT_F + ncol);             // per-lane elems

  // prologue: load iter-0 A frags + indices
  short8 afc[4];
  int idxc[4];
#pragma unroll
  for (int i = 0; i < 4; ++i)
    afc[i] = *(const short8*)(xA + (va + (u32)i * 131072u));
#pragma unroll
  for (int j = 0; j < 4; ++j) idxc[j] = ai[vi + (u32)(j * 16)];

  __syncthreads();   // centroid table ready

  const short8* csv = (const short8*)cs;
#pragma unroll 2
  for (int kt = 0; kt < KITERS; ++kt) {
    // prefetch next iteration's A frags + indices (uniform guard)
    short8 afn[4];
    int idxn[4];
    if (kt + 1 < KITERS) {
      const char* xk = xA + (va + (u32)((kt + 1) * 1024));
#pragma unroll
      for (int i = 0; i < 4; ++i)
        afn[i] = *(const short8*)(xk + (u32)i * 131072u);
      const int* an = ai + (size_t)(kt + 1) * 4 * OUT_F;
#pragma unroll
      for (int j = 0; j < 4; ++j) idxn[j] = an[vi + (u32)(j * 16)];
    }

    // gather B frags from LDS table (one 16 B lookup per lane per frag)
    short8 bfr[4];
#pragma unroll
    for (int j = 0; j < 4; ++j) bfr[j] = csv[idxc[j]];

#pragma unroll
    for (int i = 0; i < 4; ++i)
#pragma unroll
      for (int j = 0; j < 4; ++j)
        acc[i][j] = __builtin_amdgcn_mfma_f32_16x16x32_bf16(afc[i], bfr[j], acc[i][j], 0, 0, 0);

#pragma unroll
    for (int i = 0; i < 4; ++i) afc[i] = afn[i];
#pragma unroll
    for (int j = 0; j < 4; ++j) idxc[j] = idxn[j];
  }

  // ---- on-chip split-K reduction through LDS ----
  // C/D layout: col = r16 + j*16, row = wm*64 + quad*4 + r + i*16
  const int rbase = wm * 64 + quad * 4;
  if (s == 0) {
#pragma unroll
    for (int i = 0; i < 4; ++i)
#pragma unroll
      for (int j = 0; j < 4; ++j)
#pragma unroll
        for (int r = 0; r < 4; ++r)
          Cs[(rbase + i * 16 + r) * 68 + r16 + j * 16] = acc[i][j][r];
  }
  __syncthreads();
#pragma unroll
  for (int g = 1; g < 4; ++g) {
    if (s == g) {
#pragma unroll
      for (int i = 0; i < 4; ++i)
#pragma unroll
        for (int j = 0; j < 4; ++j)
#pragma unroll
          for (int r = 0; r < 4; ++r)
            Cs[(rbase + i * 16 + r) * 68 + r16 + j * 16] += acc[i][j][r];
    }
    __syncthreads();
  }

  // cooperative store: 4 passes x (32 rows x 16 float4), bias fused
  const int c4 = t & 15;
  const float4 b4 = ((const float4*)bias)[(n0 >> 2) + c4];
#pragma unroll
  for (int p = 0; p < 4; ++p) {
    const int rr = p * 32 + (t >> 4);
    float4 v = *(const float4*)&Cs[rr * 68 + c4 * 4];
    v.x += b4.x; v.y += b4.y; v.z += b4.z; v.w += b4.w;
    ((float4*)out)[(((size_t)(m0 + rr) * OUT_F + n0) >> 2) + c4] = v;
  }
}

extern "C" void kernel_launch(void* const* d_in, const int* in_sizes, int n_in,
                              void* d_out, int out_size, void* d_ws, size_t ws_size,
                              hipStream_t stream) {
  const float* x      = (const float*)d_in[0];  // [1024][4096] fp32
  const float* cent   = (const float*)d_in[1];  // [2048][8] fp32
  const float* bias   = (const float*)d_in[2];  // [4096] fp32
  const int*   assign = (const int*)d_in[3];    // [512*4096] int32
  float* out = (float*)d_out;

  // ws layout: xs (8 MB) | centb (32 KB)   -- no partials (on-chip reduce)
  const size_t xb_bytes = (size_t)NTOK * IN_F * sizeof(u16);      // 8388608
  u16* xs    = (u16*)d_ws;
  u16* centb = (u16*)((char*)d_ws + xb_bytes);

  hipLaunchKernelGGL(cast_swz_kernel, dim3(64 * 32), dim3(256), 0, stream, x, xs);
  hipLaunchKernelGGL(cast_bf16_kernel, dim3((NCENT * 8 / 8) / 256), dim3(256), 0, stream,
                     cent, centb);
  hipLaunchKernelGGL(gemm_fused_kernel, dim3(512), dim3(512), 0, stream,
                     xs, centb, assign, bias, out);
}